// Round 2
// baseline (63620.215 us; speedup 1.0000x reference)
//
#include <hip/hip_runtime.h>
#include <math.h>

// QSAR fused pipeline, one block per molecule. B=4096, A=64, D=6, AF=37, BF=6, H=128.
// Sparsity: deg==6 atoms (P~91%) output ZERO from both convs -> conv worklist (~5.8 atoms).
// x2p[a] nonzero only if a's neighborhood has a work atom (P~0.48) -> P5 compaction.

__device__ __forceinline__ float4 max4(float4 a, float4 b) {
  return make_float4(fmaxf(a.x, b.x), fmaxf(a.y, b.y), fmaxf(a.z, b.z), fmaxf(a.w, b.w));
}

__global__ __launch_bounds__(256, 3) void qsar_fused(
    const float* __restrict__ atoms, const float* __restrict__ bonds,
    const int* __restrict__ edges,
    const float* __restrict__ W1, const float* __restrict__ b1,
    const float* __restrict__ W2, const float* __restrict__ b2,
    const float* __restrict__ Wo, const float* __restrict__ bo,
    const float* __restrict__ Wm1, const float* __restrict__ bm1,
    const float* __restrict__ Wm2, const float* __restrict__ bm2,
    const float* __restrict__ Wm3, const float* __restrict__ bm3,
    float* __restrict__ out)
{
  const int b    = blockIdx.x;
  const int tid  = threadIdx.x;
  const int lane = tid & 63;
  const int wid  = tid >> 6;

  __shared__ float s_x[64 * 128];      // x1 -> x1p/ysum -> x2/x2p -> logits -> probs
  __shared__ float s_atoms[64 * 38];   // staged atom features (37 used, pad 38)
  __shared__ float s_bsum[64 * 8];     // bonds.sum(2) (6 used, pad 8)
  __shared__ int   s_edges[64 * 6];
  __shared__ int   s_deg[64];
  __shared__ int   s_work[64];         // deg<6 atoms
  __shared__ int   s_nzl[64];          // atoms with nonzero x2p row
  __shared__ int   s_zl[64];           // atoms with zero x2p row
  __shared__ int   s_nwork, s_na, s_nz;
  __shared__ float s_rsum[64];
  __shared__ float s_fp[2 * 128];
  __shared__ float s_h1[64];
  __shared__ float s_h2[32];

  float4* sx4 = reinterpret_cast<float4*>(s_x);

  // ---------------- P0a: stage + zero s_x + reset counters ----------------------------
  {
    const float* ga = atoms + (size_t)b * (64 * 37);
    for (int i = tid; i < 64 * 37; i += 256) {
      int a = i / 37, k = i - a * 37;
      s_atoms[a * 38 + k] = ga[i];
    }
    const int* ge = edges + (size_t)b * (64 * 6);
    for (int i = tid; i < 64 * 6; i += 256) s_edges[i] = ge[i];
    const float* gb = bonds + (size_t)b * (64 * 36);
    for (int i = tid; i < 64 * 6; i += 256) {
      int a = i / 6, f = i - a * 6;
      float s = 0.f;
#pragma unroll
      for (int d = 0; d < 6; ++d) s += gb[a * 36 + d * 6 + f];
      s_bsum[a * 8 + f] = s;
    }
#pragma unroll
    for (int j = 0; j < 8; ++j) sx4[tid + j * 256] = make_float4(0.f, 0.f, 0.f, 0.f);
    if (tid == 0) { s_nwork = 0; s_na = 0; s_nz = 0; }
  }
  __syncthreads();

  // ---------------- P0b: degree + worklist --------------------------------------------
  if (tid < 64) {
    int dcnt = 0;
#pragma unroll
    for (int d = 0; d < 6; ++d) dcnt += (s_edges[tid * 6 + d] >= 0) ? 1 : 0;
    s_deg[tid] = dcnt;
    if (dcnt < 6) { int p = atomicAdd(&s_nwork, 1); s_work[p] = tid; }
  }
  __syncthreads();

  // ---------------- P1: x2p-nonzero lists (tid<64) + conv1 ----------------------------
  // Lists read only in P5 (many barriers later). Conv1 reads s_atoms/s_bsum, writes s_x
  // work rows (s_x pre-zeroed; no reader of s_x in this region -> immediate writes OK).
  if (tid < 64) {
    bool nzf = (s_deg[tid] < 6);
#pragma unroll
    for (int d = 0; d < 6; ++d) {
      int e = s_edges[tid * 6 + d];
      if (e >= 0 && s_deg[e] < 6) nzf = true;
    }
    if (nzf) { int p = atomicAdd(&s_na, 1); s_nzl[p] = tid; }
    else     { int p = atomicAdd(&s_nz, 1); s_zl[p]  = tid; }
  }
  {
    const int nw = s_nwork;
    for (int w = wid; w < nw; w += 4) {
      const int a = s_work[w];
      const int d = s_deg[a];
      int  mo[6]; bool mv[6];
#pragma unroll
      for (int m = 0; m < 6; ++m) {
        int e = s_edges[a * 6 + m];
        mv[m] = (e >= 0); mo[m] = (e >= 0 ? e : 0) * 38;
      }
      const float* wp = W1 + d * (43 * 128);
      float2 bb = *reinterpret_cast<const float2*>(&b1[d * 128 + 2 * lane]);
      float acc0 = bb.x, acc1 = bb.y;
      for (int k = 0; k < 37; ++k) {
        float f = s_atoms[a * 38 + k];
#pragma unroll
        for (int m = 0; m < 6; ++m) if (mv[m]) f += s_atoms[mo[m] + k];
        float2 w2 = *reinterpret_cast<const float2*>(&wp[k * 128 + 2 * lane]);
        acc0 = fmaf(f, w2.x, acc0); acc1 = fmaf(f, w2.y, acc1);
      }
#pragma unroll
      for (int kk = 0; kk < 6; ++kk) {
        float f = s_bsum[a * 8 + kk];
        float2 w2 = *reinterpret_cast<const float2*>(&wp[(37 + kk) * 128 + 2 * lane]);
        acc0 = fmaf(f, w2.x, acc0); acc1 = fmaf(f, w2.y, acc1);
      }
      *reinterpret_cast<float2*>(&s_x[a * 128 + 2 * lane]) =
          make_float2(fmaxf(acc0, 0.f), fmaxf(acc1, 0.f));
    }
  }
  __syncthreads();

  // ---------------- P2: pool1 in place, float4 ----------------------------------------
  {
    float4 pv[8];
#pragma unroll
    for (int j = 0; j < 8; ++j) {
      int idx = tid + j * 256;          // over 2048 float4 slots
      int a = idx >> 5, c4 = idx & 31;
      float4 m = sx4[a * 32 + c4];
#pragma unroll
      for (int d = 0; d < 6; ++d) {
        int e = s_edges[a * 6 + d];
        if (e >= 0) m = max4(m, sx4[e * 32 + c4]);
      }
      pv[j] = m;
    }
    __syncthreads();
#pragma unroll
    for (int j = 0; j < 8; ++j) sx4[tid + j * 256] = pv[j];
  }
  __syncthreads();

  // ---------------- P2b: worklist neighbor-sum (ysum) into work rows, float4 ----------
  {
    const int nel = s_nwork * 32;       // float4 elements
    float4 pv[8];
#pragma unroll
    for (int j = 0; j < 8; ++j) {
      int e4 = tid + j * 256;
      if (e4 < nel) {
        int wi = e4 >> 5, c4 = e4 & 31;
        int a = s_work[wi];
        float4 s = sx4[a * 32 + c4];
#pragma unroll
        for (int d = 0; d < 6; ++d) {
          int ee = s_edges[a * 6 + d];
          if (ee >= 0) {
            float4 v = sx4[ee * 32 + c4];
            s.x += v.x; s.y += v.y; s.z += v.z; s.w += v.w;
          }
        }
        pv[j] = s;
      }
    }
    __syncthreads();
#pragma unroll
    for (int j = 0; j < 8; ++j) {
      int e4 = tid + j * 256;
      if (e4 < nel) sx4[s_work[e4 >> 5] * 32 + (e4 & 31)] = pv[j];
    }
  }
  __syncthreads();

  // ---------------- P3: conv2, own-row read / own-row write ---------------------------
  // Non-work rows keep STALE x1p values; pool2 below ignores them (work members only).
  {
    const int nw = s_nwork;
    for (int w = wid; w < nw; w += 4) {
      const int a = s_work[w];
      const int d = s_deg[a];
      const float* wp = W2 + d * (134 * 128);
      float2 bb = *reinterpret_cast<const float2*>(&b2[d * 128 + 2 * lane]);
      float acc0 = bb.x, acc1 = bb.y;
      for (int k = 0; k < 128; ++k) {
        float f = s_x[a * 128 + k];
        float2 w2 = *reinterpret_cast<const float2*>(&wp[k * 128 + 2 * lane]);
        acc0 = fmaf(f, w2.x, acc0); acc1 = fmaf(f, w2.y, acc1);
      }
#pragma unroll
      for (int kk = 0; kk < 6; ++kk) {
        float f = s_bsum[a * 8 + kk];
        float2 w2 = *reinterpret_cast<const float2*>(&wp[(128 + kk) * 128 + 2 * lane]);
        acc0 = fmaf(f, w2.x, acc0); acc1 = fmaf(f, w2.y, acc1);
      }
      // all lanes' reads of row a precede this write in wave program order
      *reinterpret_cast<float2*>(&s_x[a * 128 + 2 * lane]) =
          make_float2(fmaxf(acc0, 0.f), fmaxf(acc1, 0.f));
    }
  }
  __syncthreads();

  // ---------------- P4: pool2 in place, float4, max over WORK members only ------------
  // x2 rows are relu>=0 and implicitly 0 elsewhere -> m=0 init is exact.
  {
    float4 pv[8];
#pragma unroll
    for (int j = 0; j < 8; ++j) {
      int idx = tid + j * 256;
      int a = idx >> 5, c4 = idx & 31;
      float4 m = make_float4(0.f, 0.f, 0.f, 0.f);
      if (s_deg[a] < 6) m = max4(m, sx4[a * 32 + c4]);
#pragma unroll
      for (int d = 0; d < 6; ++d) {
        int e = s_edges[a * 6 + d];
        if (e >= 0 && s_deg[e] < 6) m = max4(m, sx4[e * 32 + c4]);
      }
      pv[j] = m;
    }
    __syncthreads();
#pragma unroll
    for (int j = 0; j < 8; ++j) sx4[tid + j * 256] = pv[j];
  }
  __syncthreads();

  // ---------------- P5: logits. Compacted dense path (nonzero x2p) + cheap zero path --
  {
    const int cg = tid & 31, ag = tid >> 5;
    const int c0 = cg * 4;
    const int na = s_na, nz = s_nz;

    float accB[8][4];
    int   atB[8];
#pragma unroll
    for (int g = 0; g < 8; ++g) {
      int p = g * 8 + ag;
      atB[g] = (p < na) ? s_nzl[p] : -1;
      accB[g][0] = 0.f; accB[g][1] = 0.f; accB[g][2] = 0.f; accB[g][3] = 0.f;
    }
    for (int k = 0; k < 128; ++k) {
      const float4 w4 = *reinterpret_cast<const float4*>(Wo + k * 128 + c0);
#pragma unroll
      for (int g = 0; g < 8; ++g) {
        if (atB[g] >= 0) {
          const float f = s_x[atB[g] * 128 + k];
          accB[g][0] = fmaf(f, w4.x, accB[g][0]);
          accB[g][1] = fmaf(f, w4.y, accB[g][1]);
          accB[g][2] = fmaf(f, w4.z, accB[g][2]);
          accB[g][3] = fmaf(f, w4.w, accB[g][3]);
        }
      }
    }
#pragma unroll
    for (int kk = 0; kk < 6; ++kk) {
      const float4 w4 = *reinterpret_cast<const float4*>(Wo + (128 + kk) * 128 + c0);
#pragma unroll
      for (int g = 0; g < 8; ++g) {
        if (atB[g] >= 0) {
          const float f = s_bsum[atB[g] * 8 + kk];
          accB[g][0] = fmaf(f, w4.x, accB[g][0]);
          accB[g][1] = fmaf(f, w4.y, accB[g][1]);
          accB[g][2] = fmaf(f, w4.z, accB[g][2]);
          accB[g][3] = fmaf(f, w4.w, accB[g][3]);
        }
      }
    }
    __syncthreads();   // all x2p reads done
    const float4 bo4 = *reinterpret_cast<const float4*>(bo + c0);
#pragma unroll
    for (int g = 0; g < 8; ++g) {
      if (atB[g] >= 0) {
        *reinterpret_cast<float4*>(&s_x[atB[g] * 128 + c0]) =
            make_float4(accB[g][0] + bo4.x, accB[g][1] + bo4.y,
                        accB[g][2] + bo4.z, accB[g][3] + bo4.w);
      }
    }
    // zero-x2p atoms: logits = bo + bsum . Wo[128:134]  (reads no s_x; z-rows unread)
    for (int e = tid; e < nz * 128; e += 256) {
      int zi = e >> 7, c = e & 127;
      int a = s_zl[zi];
      float acc = bo[c];
#pragma unroll
      for (int kk = 0; kk < 6; ++kk)
        acc = fmaf(s_bsum[a * 8 + kk], Wo[(128 + kk) * 128 + c], acc);
      s_x[a * 128 + c] = acc;
    }
  }
  __syncthreads();

  // ---------------- P6: per-atom softmax over 128 (in place), 4 lanes/atom ------------
  {
    const int a = tid >> 2, q = tid & 3;
    const int base = a * 128 + q * 32;
    float mx = -3.0e38f;
    for (int j = 0; j < 32; ++j) {
      int jj = (j + tid) & 31;
      mx = fmaxf(mx, s_x[base + jj]);
    }
    mx = fmaxf(mx, __shfl_xor(mx, 1));
    mx = fmaxf(mx, __shfl_xor(mx, 2));
    float sm = 0.f;
    for (int j = 0; j < 32; ++j) {
      int jj = (j + tid) & 31;
      float e = __expf(s_x[base + jj] - mx);
      sm += e;
      s_x[base + jj] = e;
    }
    sm += __shfl_xor(sm, 1);
    sm += __shfl_xor(sm, 2);
    if (q == 0) s_rsum[a] = (s_deg[a] != 0) ? (1.f / sm) : 0.f;
  }
  __syncthreads();

  // ---------------- P7: fingerprint ---------------------------------------------------
  {
    const int c = tid & 127, half = tid >> 7;
    float s = 0.f;
    for (int a2 = half * 32; a2 < half * 32 + 32; ++a2)
      s = fmaf(s_x[a2 * 128 + c], s_rsum[a2], s);
    s_fp[half * 128 + c] = s;
  }
  __syncthreads();
  if (tid < 128) s_fp[tid] += s_fp[128 + tid];
  __syncthreads();

  // ---------------- P8: MLP head ------------------------------------------------------
  if (tid < 64) {
    float acc = bm1[tid];
    for (int k = 0; k < 128; ++k) acc = fmaf(s_fp[k], Wm1[k * 64 + tid], acc);
    s_h1[tid] = fmaxf(acc, 0.f);
  }
  __syncthreads();
  if (tid < 32) {
    float acc = bm2[tid];
    for (int k = 0; k < 64; ++k) acc = fmaf(s_h1[k], Wm2[k * 32 + tid], acc);
    s_h2[tid] = fmaxf(acc, 0.f);
  }
  __syncthreads();
  if (tid < 64) {
    float p = (tid < 32) ? s_h2[tid] * Wm3[tid] : 0.f;
#pragma unroll
    for (int off = 32; off > 0; off >>= 1) p += __shfl_xor(p, off);
    if (tid == 0) out[b] = p + bm3[0];
  }
}

extern "C" void kernel_launch(void* const* d_in, const int* in_sizes, int n_in,
                              void* d_out, int out_size, void* d_ws, size_t ws_size,
                              hipStream_t stream) {
  const float* atoms = (const float*)d_in[0];
  const float* bonds = (const float*)d_in[1];
  const int*   edges = (const int*)d_in[2];
  const float* W1  = (const float*)d_in[3];
  const float* b1  = (const float*)d_in[4];
  const float* W2  = (const float*)d_in[5];
  const float* b2  = (const float*)d_in[6];
  const float* Wo  = (const float*)d_in[7];
  const float* bo  = (const float*)d_in[8];
  const float* Wm1 = (const float*)d_in[9];
  const float* bm1 = (const float*)d_in[10];
  const float* Wm2 = (const float*)d_in[11];
  const float* bm2 = (const float*)d_in[12];
  const float* Wm3 = (const float*)d_in[13];
  const float* bm3 = (const float*)d_in[14];
  float* out = (float*)d_out;

  const int B = out_size;  // 4096 molecules
  qsar_fused<<<dim3(B), dim3(256), 0, stream>>>(
      atoms, bonds, edges, W1, b1, W2, b2, Wo, bo,
      Wm1, bm1, Wm2, bm2, Wm3, bm3, out);
}

// Round 3
// 283.552 us; speedup vs baseline: 224.3684x; 224.3684x over previous
//
#include <hip/hip_runtime.h>
#include <math.h>

// QSAR fused pipeline, one block per molecule. B=4096, A=64, D=6, AF=37, BF=6, H=128.
// deg==6 atoms (P~91%) output ZERO from both convs -> conv worklist (~5.8 atoms/block).
// x2p[a] != 0 only if a's neighborhood contains a work atom (P~0.48) -> P5 block-skip
// via a permutation (nonzero rows first), with UNCONDITIONAL accumulator updates
// (R2's predicated-accumulator form spilled to scratch: 363 GB HBM writes).

__device__ __forceinline__ float4 max4(float4 a, float4 b) {
  return make_float4(fmaxf(a.x, b.x), fmaxf(a.y, b.y), fmaxf(a.z, b.z), fmaxf(a.w, b.w));
}

__device__ __forceinline__ float4 nbr_max(const float4* sx4, const int* se, int a, int c4) {
  float4 m = sx4[a * 32 + c4];
#pragma unroll
  for (int d = 0; d < 6; ++d) {
    int e = se[a * 6 + d];
    if (e >= 0) m = max4(m, sx4[e * 32 + c4]);
  }
  return m;
}

__device__ __forceinline__ float4 nbr_sum(const float4* sx4, const int* se, int a, int c4) {
  float4 s = sx4[a * 32 + c4];
#pragma unroll
  for (int d = 0; d < 6; ++d) {
    int e = se[a * 6 + d];
    if (e >= 0) {
      float4 v = sx4[e * 32 + c4];
      s.x += v.x; s.y += v.y; s.z += v.z; s.w += v.w;
    }
  }
  return s;
}

// pool2: max over WORK members only; x2 rows of non-work atoms are implicitly 0 and
// relu(x2) >= 0, so 0-init is exact. Non-work s_x rows hold stale data, never read.
__device__ __forceinline__ float4 nbr_wmax(const float4* sx4, const int* se, const int* sdeg,
                                           int a, int c4) {
  float4 m = make_float4(0.f, 0.f, 0.f, 0.f);
  if (sdeg[a] < 6) m = max4(m, sx4[a * 32 + c4]);
#pragma unroll
  for (int d = 0; d < 6; ++d) {
    int e = se[a * 6 + d];
    if (e >= 0 && sdeg[e] < 6) m = max4(m, sx4[e * 32 + c4]);
  }
  return m;
}

__global__ __launch_bounds__(256, 4) void qsar_fused(
    const float* __restrict__ atoms, const float* __restrict__ bonds,
    const int* __restrict__ edges,
    const float* __restrict__ W1, const float* __restrict__ b1,
    const float* __restrict__ W2, const float* __restrict__ b2,
    const float* __restrict__ Wo, const float* __restrict__ bo,
    const float* __restrict__ Wm1, const float* __restrict__ bm1,
    const float* __restrict__ Wm2, const float* __restrict__ bm2,
    const float* __restrict__ Wm3, const float* __restrict__ bm3,
    float* __restrict__ out)
{
  const int b    = blockIdx.x;
  const int tid  = threadIdx.x;
  const int lane = tid & 63;
  const int wid  = tid >> 6;

  __shared__ float s_x[64 * 128];     // 32768 B: x1 -> x1p -> ysum -> x2 -> x2p -> logits -> probs
  __shared__ float s_sa[16 * 38];     // 2432 B: chunked summed-atom feats; later fp/h1/h2
  __shared__ float s_bsum[64 * 8];    // 2048 B
  __shared__ int   s_edges[64 * 6];   // 1536 B
  __shared__ int   s_deg[64];
  __shared__ int   s_work[64];        // deg<6 atoms
  __shared__ int   s_perm[64];        // perm: nonzero-x2p atoms [0,na), zero atoms [na,64)
  __shared__ float s_rsum[64];
  __shared__ int   s_nwork, s_na, s_nz;

  float4* sx4  = reinterpret_cast<float4*>(s_x);
  float*  s_fp = s_sa;                // 256 floats (alias; s_sa dead after conv1)
  float*  s_h1 = s_sa + 256;          // 64
  float*  s_h2 = s_sa + 320;          // 32

  // ---------------- P0: stage edges, bsum; zero s_x; reset counters -------------------
  {
    const int* ge = edges + (size_t)b * (64 * 6);
    for (int i = tid; i < 64 * 6; i += 256) s_edges[i] = ge[i];
    const float* gb = bonds + (size_t)b * (64 * 36);
    for (int i = tid; i < 64 * 6; i += 256) {
      int a = i / 6, f = i - a * 6;
      float s = 0.f;
#pragma unroll
      for (int d = 0; d < 6; ++d) s += gb[a * 36 + d * 6 + f];
      s_bsum[a * 8 + f] = s;
    }
#pragma unroll
    for (int j = 0; j < 8; ++j) sx4[tid + j * 256] = make_float4(0.f, 0.f, 0.f, 0.f);
    if (tid == 0) { s_nwork = 0; s_na = 0; s_nz = 0; }
  }
  __syncthreads();

  // ---------------- P0b: degree + worklist --------------------------------------------
  if (tid < 64) {
    int dcnt = 0;
#pragma unroll
    for (int d = 0; d < 6; ++d) dcnt += (s_edges[tid * 6 + d] >= 0) ? 1 : 0;
    s_deg[tid] = dcnt;
    if (dcnt < 6) { int p = atomicAdd(&s_nwork, 1); s_work[p] = tid; }
  }
  __syncthreads();

  // ---------------- P0c: perm (nonzero-x2p first; read only in P5, many barriers later)
  if (tid < 64) {
    int nzf = (s_deg[tid] < 6) ? 1 : 0;
#pragma unroll
    for (int d = 0; d < 6; ++d) {
      int e = s_edges[tid * 6 + d];
      if (e >= 0 && s_deg[e] < 6) nzf = 1;
    }
    if (nzf) { int p = atomicAdd(&s_na, 1); s_perm[p] = tid; }
    else     { int p = atomicAdd(&s_nz, 1); s_perm[63 - p] = tid; }
  }

  // ---------------- P1: conv1 in chunks of <=16 work atoms ----------------------------
  {
    const int nw = s_nwork;
    const float* ga = atoms + (size_t)b * (64 * 37);
    for (int cb = 0; cb < nw; cb += 16) {
      const int cnt = (nw - cb < 16) ? (nw - cb) : 16;
      // P1a: gather summed feats (self + valid members) from global into s_sa
      for (int i = tid; i < cnt * 37; i += 256) {
        int wi = i / 37, k = i - wi * 37;
        int a = s_work[cb + wi];
        float f = ga[a * 37 + k];
#pragma unroll
        for (int d = 0; d < 6; ++d) {
          int e = s_edges[a * 6 + d];
          if (e >= 0) f += ga[e * 37 + k];
        }
        s_sa[wi * 38 + k] = f;
      }
      __syncthreads();
      // P1b: conv1 GEMV per wave; writes s_x work rows (s_x pre-zeroed; no s_x readers here)
      for (int w = wid; w < cnt; w += 4) {
        const int a = s_work[cb + w];
        const int d = s_deg[a];
        const float* wp = W1 + d * (43 * 128);
        float2 bb = *reinterpret_cast<const float2*>(&b1[d * 128 + 2 * lane]);
        float acc0 = bb.x, acc1 = bb.y;
        for (int k = 0; k < 37; ++k) {
          float f = s_sa[w * 38 + k];
          float2 w2 = *reinterpret_cast<const float2*>(&wp[k * 128 + 2 * lane]);
          acc0 = fmaf(f, w2.x, acc0); acc1 = fmaf(f, w2.y, acc1);
        }
#pragma unroll
        for (int kk = 0; kk < 6; ++kk) {
          float f = s_bsum[a * 8 + kk];
          float2 w2 = *reinterpret_cast<const float2*>(&wp[(37 + kk) * 128 + 2 * lane]);
          acc0 = fmaf(f, w2.x, acc0); acc1 = fmaf(f, w2.y, acc1);
        }
        *reinterpret_cast<float2*>(&s_x[a * 128 + 2 * lane]) =
            make_float2(fmaxf(acc0, 0.f), fmaxf(acc1, 0.f));
      }
      __syncthreads();
    }
  }
  __syncthreads();

  // ---------------- P2: pool1 in place (all rows), float4, named regs -----------------
  {
    float4 v0 = nbr_max(sx4, s_edges, (tid + 0 * 256) >> 5, tid & 31);
    float4 v1 = nbr_max(sx4, s_edges, (tid + 1 * 256) >> 5, tid & 31);
    float4 v2 = nbr_max(sx4, s_edges, (tid + 2 * 256) >> 5, tid & 31);
    float4 v3 = nbr_max(sx4, s_edges, (tid + 3 * 256) >> 5, tid & 31);
    float4 v4 = nbr_max(sx4, s_edges, (tid + 4 * 256) >> 5, tid & 31);
    float4 v5 = nbr_max(sx4, s_edges, (tid + 5 * 256) >> 5, tid & 31);
    float4 v6 = nbr_max(sx4, s_edges, (tid + 6 * 256) >> 5, tid & 31);
    float4 v7 = nbr_max(sx4, s_edges, (tid + 7 * 256) >> 5, tid & 31);
    __syncthreads();
    sx4[tid + 0 * 256] = v0; sx4[tid + 1 * 256] = v1;
    sx4[tid + 2 * 256] = v2; sx4[tid + 3 * 256] = v3;
    sx4[tid + 4 * 256] = v4; sx4[tid + 5 * 256] = v5;
    sx4[tid + 6 * 256] = v6; sx4[tid + 7 * 256] = v7;
  }
  __syncthreads();

  // ---------------- P2b: ysum for work rows in place (conditional per row, R1 pattern)
  {
    const float4 z = make_float4(0.f, 0.f, 0.f, 0.f);
    float4 v0 = z, v1 = z, v2 = z, v3 = z, v4 = z, v5 = z, v6 = z, v7 = z;
    if (s_deg[(tid + 0 * 256) >> 5] < 6) v0 = nbr_sum(sx4, s_edges, (tid + 0 * 256) >> 5, tid & 31);
    if (s_deg[(tid + 1 * 256) >> 5] < 6) v1 = nbr_sum(sx4, s_edges, (tid + 1 * 256) >> 5, tid & 31);
    if (s_deg[(tid + 2 * 256) >> 5] < 6) v2 = nbr_sum(sx4, s_edges, (tid + 2 * 256) >> 5, tid & 31);
    if (s_deg[(tid + 3 * 256) >> 5] < 6) v3 = nbr_sum(sx4, s_edges, (tid + 3 * 256) >> 5, tid & 31);
    if (s_deg[(tid + 4 * 256) >> 5] < 6) v4 = nbr_sum(sx4, s_edges, (tid + 4 * 256) >> 5, tid & 31);
    if (s_deg[(tid + 5 * 256) >> 5] < 6) v5 = nbr_sum(sx4, s_edges, (tid + 5 * 256) >> 5, tid & 31);
    if (s_deg[(tid + 6 * 256) >> 5] < 6) v6 = nbr_sum(sx4, s_edges, (tid + 6 * 256) >> 5, tid & 31);
    if (s_deg[(tid + 7 * 256) >> 5] < 6) v7 = nbr_sum(sx4, s_edges, (tid + 7 * 256) >> 5, tid & 31);
    __syncthreads();
    if (s_deg[(tid + 0 * 256) >> 5] < 6) sx4[tid + 0 * 256] = v0;
    if (s_deg[(tid + 1 * 256) >> 5] < 6) sx4[tid + 1 * 256] = v1;
    if (s_deg[(tid + 2 * 256) >> 5] < 6) sx4[tid + 2 * 256] = v2;
    if (s_deg[(tid + 3 * 256) >> 5] < 6) sx4[tid + 3 * 256] = v3;
    if (s_deg[(tid + 4 * 256) >> 5] < 6) sx4[tid + 4 * 256] = v4;
    if (s_deg[(tid + 5 * 256) >> 5] < 6) sx4[tid + 5 * 256] = v5;
    if (s_deg[(tid + 6 * 256) >> 5] < 6) sx4[tid + 6 * 256] = v6;
    if (s_deg[(tid + 7 * 256) >> 5] < 6) sx4[tid + 7 * 256] = v7;
  }
  __syncthreads();

  // ---------------- P3: conv2, own-row read / own-row write (wave lockstep) -----------
  {
    const int nw = s_nwork;
    for (int w = wid; w < nw; w += 4) {
      const int a = s_work[w];
      const int d = s_deg[a];
      const float* wp = W2 + d * (134 * 128);
      float2 bb = *reinterpret_cast<const float2*>(&b2[d * 128 + 2 * lane]);
      float acc0 = bb.x, acc1 = bb.y;
      for (int k = 0; k < 128; ++k) {
        float f = s_x[a * 128 + k];
        float2 w2 = *reinterpret_cast<const float2*>(&wp[k * 128 + 2 * lane]);
        acc0 = fmaf(f, w2.x, acc0); acc1 = fmaf(f, w2.y, acc1);
      }
#pragma unroll
      for (int kk = 0; kk < 6; ++kk) {
        float f = s_bsum[a * 8 + kk];
        float2 w2 = *reinterpret_cast<const float2*>(&wp[(128 + kk) * 128 + 2 * lane]);
        acc0 = fmaf(f, w2.x, acc0); acc1 = fmaf(f, w2.y, acc1);
      }
      *reinterpret_cast<float2*>(&s_x[a * 128 + 2 * lane]) =
          make_float2(fmaxf(acc0, 0.f), fmaxf(acc1, 0.f));
    }
  }
  __syncthreads();

  // ---------------- P4: pool2 in place, work members only, 0-init ---------------------
  {
    float4 v0 = nbr_wmax(sx4, s_edges, s_deg, (tid + 0 * 256) >> 5, tid & 31);
    float4 v1 = nbr_wmax(sx4, s_edges, s_deg, (tid + 1 * 256) >> 5, tid & 31);
    float4 v2 = nbr_wmax(sx4, s_edges, s_deg, (tid + 2 * 256) >> 5, tid & 31);
    float4 v3 = nbr_wmax(sx4, s_edges, s_deg, (tid + 3 * 256) >> 5, tid & 31);
    float4 v4 = nbr_wmax(sx4, s_edges, s_deg, (tid + 4 * 256) >> 5, tid & 31);
    float4 v5 = nbr_wmax(sx4, s_edges, s_deg, (tid + 5 * 256) >> 5, tid & 31);
    float4 v6 = nbr_wmax(sx4, s_edges, s_deg, (tid + 6 * 256) >> 5, tid & 31);
    float4 v7 = nbr_wmax(sx4, s_edges, s_deg, (tid + 7 * 256) >> 5, tid & 31);
    __syncthreads();
    sx4[tid + 0 * 256] = v0; sx4[tid + 1 * 256] = v1;
    sx4[tid + 2 * 256] = v2; sx4[tid + 3 * 256] = v3;
    sx4[tid + 4 * 256] = v4; sx4[tid + 5 * 256] = v5;
    sx4[tid + 6 * 256] = v6; sx4[tid + 7 * 256] = v7;
  }
  __syncthreads();

  // ---------------- P5: logits GEMM over perm; skip all-zero 8-atom groups ------------
  // Group g owns perm[p0..p0+8). acc updates UNCONDITIONAL (spill-safe); groups with
  // p0 >= na skip the 128-deep loop (their x2p rows are exactly zero). Straddle group
  // computes zero rows densely (adds 0). bsum tail + bias runs for ALL atoms.
  {
    const int cg = tid & 31, ag = tid >> 5;
    const int c0 = cg * 4, p0 = ag * 8;
    const int na = s_na;
    int at0 = s_perm[p0 + 0], at1 = s_perm[p0 + 1], at2 = s_perm[p0 + 2], at3 = s_perm[p0 + 3];
    int at4 = s_perm[p0 + 4], at5 = s_perm[p0 + 5], at6 = s_perm[p0 + 6], at7 = s_perm[p0 + 7];
    float acc[8][4];
#pragma unroll
    for (int g = 0; g < 8; ++g) { acc[g][0] = 0.f; acc[g][1] = 0.f; acc[g][2] = 0.f; acc[g][3] = 0.f; }
    if (p0 < na) {
      for (int k = 0; k < 128; ++k) {
        const float4 w4 = *reinterpret_cast<const float4*>(Wo + k * 128 + c0);
        const float f0 = s_x[at0 * 128 + k], f1 = s_x[at1 * 128 + k];
        const float f2 = s_x[at2 * 128 + k], f3 = s_x[at3 * 128 + k];
        const float f4 = s_x[at4 * 128 + k], f5 = s_x[at5 * 128 + k];
        const float f6 = s_x[at6 * 128 + k], f7 = s_x[at7 * 128 + k];
        acc[0][0] = fmaf(f0, w4.x, acc[0][0]); acc[0][1] = fmaf(f0, w4.y, acc[0][1]);
        acc[0][2] = fmaf(f0, w4.z, acc[0][2]); acc[0][3] = fmaf(f0, w4.w, acc[0][3]);
        acc[1][0] = fmaf(f1, w4.x, acc[1][0]); acc[1][1] = fmaf(f1, w4.y, acc[1][1]);
        acc[1][2] = fmaf(f1, w4.z, acc[1][2]); acc[1][3] = fmaf(f1, w4.w, acc[1][3]);
        acc[2][0] = fmaf(f2, w4.x, acc[2][0]); acc[2][1] = fmaf(f2, w4.y, acc[2][1]);
        acc[2][2] = fmaf(f2, w4.z, acc[2][2]); acc[2][3] = fmaf(f2, w4.w, acc[2][3]);
        acc[3][0] = fmaf(f3, w4.x, acc[3][0]); acc[3][1] = fmaf(f3, w4.y, acc[3][1]);
        acc[3][2] = fmaf(f3, w4.z, acc[3][2]); acc[3][3] = fmaf(f3, w4.w, acc[3][3]);
        acc[4][0] = fmaf(f4, w4.x, acc[4][0]); acc[4][1] = fmaf(f4, w4.y, acc[4][1]);
        acc[4][2] = fmaf(f4, w4.z, acc[4][2]); acc[4][3] = fmaf(f4, w4.w, acc[4][3]);
        acc[5][0] = fmaf(f5, w4.x, acc[5][0]); acc[5][1] = fmaf(f5, w4.y, acc[5][1]);
        acc[5][2] = fmaf(f5, w4.z, acc[5][2]); acc[5][3] = fmaf(f5, w4.w, acc[5][3]);
        acc[6][0] = fmaf(f6, w4.x, acc[6][0]); acc[6][1] = fmaf(f6, w4.y, acc[6][1]);
        acc[6][2] = fmaf(f6, w4.z, acc[6][2]); acc[6][3] = fmaf(f6, w4.w, acc[6][3]);
        acc[7][0] = fmaf(f7, w4.x, acc[7][0]); acc[7][1] = fmaf(f7, w4.y, acc[7][1]);
        acc[7][2] = fmaf(f7, w4.z, acc[7][2]); acc[7][3] = fmaf(f7, w4.w, acc[7][3]);
      }
    }
#pragma unroll
    for (int kk = 0; kk < 6; ++kk) {
      const float4 w4 = *reinterpret_cast<const float4*>(Wo + (128 + kk) * 128 + c0);
      const float f0 = s_bsum[at0 * 8 + kk], f1 = s_bsum[at1 * 8 + kk];
      const float f2 = s_bsum[at2 * 8 + kk], f3 = s_bsum[at3 * 8 + kk];
      const float f4 = s_bsum[at4 * 8 + kk], f5 = s_bsum[at5 * 8 + kk];
      const float f6 = s_bsum[at6 * 8 + kk], f7 = s_bsum[at7 * 8 + kk];
      acc[0][0] = fmaf(f0, w4.x, acc[0][0]); acc[0][1] = fmaf(f0, w4.y, acc[0][1]);
      acc[0][2] = fmaf(f0, w4.z, acc[0][2]); acc[0][3] = fmaf(f0, w4.w, acc[0][3]);
      acc[1][0] = fmaf(f1, w4.x, acc[1][0]); acc[1][1] = fmaf(f1, w4.y, acc[1][1]);
      acc[1][2] = fmaf(f1, w4.z, acc[1][2]); acc[1][3] = fmaf(f1, w4.w, acc[1][3]);
      acc[2][0] = fmaf(f2, w4.x, acc[2][0]); acc[2][1] = fmaf(f2, w4.y, acc[2][1]);
      acc[2][2] = fmaf(f2, w4.z, acc[2][2]); acc[2][3] = fmaf(f2, w4.w, acc[2][3]);
      acc[3][0] = fmaf(f3, w4.x, acc[3][0]); acc[3][1] = fmaf(f3, w4.y, acc[3][1]);
      acc[3][2] = fmaf(f3, w4.z, acc[3][2]); acc[3][3] = fmaf(f3, w4.w, acc[3][3]);
      acc[4][0] = fmaf(f4, w4.x, acc[4][0]); acc[4][1] = fmaf(f4, w4.y, acc[4][1]);
      acc[4][2] = fmaf(f4, w4.z, acc[4][2]); acc[4][3] = fmaf(f4, w4.w, acc[4][3]);
      acc[5][0] = fmaf(f5, w4.x, acc[5][0]); acc[5][1] = fmaf(f5, w4.y, acc[5][1]);
      acc[5][2] = fmaf(f5, w4.z, acc[5][2]); acc[5][3] = fmaf(f5, w4.w, acc[5][3]);
      acc[6][0] = fmaf(f6, w4.x, acc[6][0]); acc[6][1] = fmaf(f6, w4.y, acc[6][1]);
      acc[6][2] = fmaf(f6, w4.z, acc[6][2]); acc[6][3] = fmaf(f6, w4.w, acc[6][3]);
      acc[7][0] = fmaf(f7, w4.x, acc[7][0]); acc[7][1] = fmaf(f7, w4.y, acc[7][1]);
      acc[7][2] = fmaf(f7, w4.z, acc[7][2]); acc[7][3] = fmaf(f7, w4.w, acc[7][3]);
    }
    __syncthreads();   // all x2p reads done before logits overwrite
    const float4 bo4 = *reinterpret_cast<const float4*>(bo + c0);
    *reinterpret_cast<float4*>(&s_x[at0 * 128 + c0]) =
        make_float4(acc[0][0] + bo4.x, acc[0][1] + bo4.y, acc[0][2] + bo4.z, acc[0][3] + bo4.w);
    *reinterpret_cast<float4*>(&s_x[at1 * 128 + c0]) =
        make_float4(acc[1][0] + bo4.x, acc[1][1] + bo4.y, acc[1][2] + bo4.z, acc[1][3] + bo4.w);
    *reinterpret_cast<float4*>(&s_x[at2 * 128 + c0]) =
        make_float4(acc[2][0] + bo4.x, acc[2][1] + bo4.y, acc[2][2] + bo4.z, acc[2][3] + bo4.w);
    *reinterpret_cast<float4*>(&s_x[at3 * 128 + c0]) =
        make_float4(acc[3][0] + bo4.x, acc[3][1] + bo4.y, acc[3][2] + bo4.z, acc[3][3] + bo4.w);
    *reinterpret_cast<float4*>(&s_x[at4 * 128 + c0]) =
        make_float4(acc[4][0] + bo4.x, acc[4][1] + bo4.y, acc[4][2] + bo4.z, acc[4][3] + bo4.w);
    *reinterpret_cast<float4*>(&s_x[at5 * 128 + c0]) =
        make_float4(acc[5][0] + bo4.x, acc[5][1] + bo4.y, acc[5][2] + bo4.z, acc[5][3] + bo4.w);
    *reinterpret_cast<float4*>(&s_x[at6 * 128 + c0]) =
        make_float4(acc[6][0] + bo4.x, acc[6][1] + bo4.y, acc[6][2] + bo4.z, acc[6][3] + bo4.w);
    *reinterpret_cast<float4*>(&s_x[at7 * 128 + c0]) =
        make_float4(acc[7][0] + bo4.x, acc[7][1] + bo4.y, acc[7][2] + bo4.z, acc[7][3] + bo4.w);
  }
  __syncthreads();

  // ---------------- P6: per-atom softmax over 128 (in place), 4 lanes/atom ------------
  {
    const int a = tid >> 2, q = tid & 3;
    const int base = a * 128 + q * 32;
    float mx = -3.0e38f;
    for (int j = 0; j < 32; ++j) {
      int jj = (j + tid) & 31;
      mx = fmaxf(mx, s_x[base + jj]);
    }
    mx = fmaxf(mx, __shfl_xor(mx, 1));
    mx = fmaxf(mx, __shfl_xor(mx, 2));
    float sm = 0.f;
    for (int j = 0; j < 32; ++j) {
      int jj = (j + tid) & 31;
      float e = __expf(s_x[base + jj] - mx);
      sm += e;
      s_x[base + jj] = e;
    }
    sm += __shfl_xor(sm, 1);
    sm += __shfl_xor(sm, 2);
    if (q == 0) s_rsum[a] = (s_deg[a] != 0) ? (1.f / sm) : 0.f;
  }
  __syncthreads();

  // ---------------- P7: fingerprint (s_fp aliases dead s_sa) --------------------------
  {
    const int c = tid & 127, half = tid >> 7;
    float s = 0.f;
    for (int a2 = half * 32; a2 < half * 32 + 32; ++a2)
      s = fmaf(s_x[a2 * 128 + c], s_rsum[a2], s);
    s_fp[half * 128 + c] = s;
  }
  __syncthreads();
  if (tid < 128) s_fp[tid] += s_fp[128 + tid];
  __syncthreads();

  // ---------------- P8: MLP head ------------------------------------------------------
  if (tid < 64) {
    float acc = bm1[tid];
    for (int k = 0; k < 128; ++k) acc = fmaf(s_fp[k], Wm1[k * 64 + tid], acc);
    s_h1[tid] = fmaxf(acc, 0.f);
  }
  __syncthreads();
  if (tid < 32) {
    float acc = bm2[tid];
    for (int k = 0; k < 64; ++k) acc = fmaf(s_h1[k], Wm2[k * 32 + tid], acc);
    s_h2[tid] = fmaxf(acc, 0.f);
  }
  __syncthreads();
  if (tid < 64) {
    float p = (tid < 32) ? s_h2[tid] * Wm3[tid] : 0.f;
#pragma unroll
    for (int off = 32; off > 0; off >>= 1) p += __shfl_xor(p, off);
    if (tid == 0) out[b] = p + bm3[0];
  }
}

extern "C" void kernel_launch(void* const* d_in, const int* in_sizes, int n_in,
                              void* d_out, int out_size, void* d_ws, size_t ws_size,
                              hipStream_t stream) {
  const float* atoms = (const float*)d_in[0];
  const float* bonds = (const float*)d_in[1];
  const int*   edges = (const int*)d_in[2];
  const float* W1  = (const float*)d_in[3];
  const float* b1  = (const float*)d_in[4];
  const float* W2  = (const float*)d_in[5];
  const float* b2  = (const float*)d_in[6];
  const float* Wo  = (const float*)d_in[7];
  const float* bo  = (const float*)d_in[8];
  const float* Wm1 = (const float*)d_in[9];
  const float* bm1 = (const float*)d_in[10];
  const float* Wm2 = (const float*)d_in[11];
  const float* bm2 = (const float*)d_in[12];
  const float* Wm3 = (const float*)d_in[13];
  const float* bm3 = (const float*)d_in[14];
  float* out = (float*)d_out;

  const int B = out_size;  // 4096 molecules
  qsar_fused<<<dim3(B), dim3(256), 0, stream>>>(
      atoms, bonds, edges, W1, b1, W2, b2, Wo, bo,
      Wm1, bm1, Wm2, bm2, Wm3, bm3, out);
}

// Round 4
// 245.767 us; speedup vs baseline: 258.8639x; 1.1537x over previous
//
#include <hip/hip_runtime.h>
#include <math.h>

// QSAR fused pipeline, one block per molecule. B=4096, A=64, D=6, AF=37, BF=6, H=128.
// deg==6 atoms (P~91%) output ZERO from both convs -> conv worklist (~5.8 atoms/block).
// x2p[a] != 0 only if a's closed neighborhood has a work atom (P~0.47, na~30) -> P5
// runs only nonzero rows, balanced: each 32-thread group takes 4 perm atoms/round.
// Spill discipline (R2 lesson): named registers, unconditional accumulator updates,
// conditional WRITES only, uniform-trip barrier loops.

__device__ __forceinline__ float4 max4(float4 a, float4 b) {
  return make_float4(fmaxf(a.x, b.x), fmaxf(a.y, b.y), fmaxf(a.z, b.z), fmaxf(a.w, b.w));
}

__device__ __forceinline__ float4 nbr_max(const float4* sx4, const int* se, int a, int c4) {
  float4 m = sx4[a * 32 + c4];
#pragma unroll
  for (int d = 0; d < 6; ++d) {
    int e = se[a * 6 + d];
    if (e >= 0) m = max4(m, sx4[e * 32 + c4]);
  }
  return m;
}

__device__ __forceinline__ float4 nbr_sum(const float4* sx4, const int* se, int a, int c4) {
  float4 s = sx4[a * 32 + c4];
#pragma unroll
  for (int d = 0; d < 6; ++d) {
    int e = se[a * 6 + d];
    if (e >= 0) {
      float4 v = sx4[e * 32 + c4];
      s.x += v.x; s.y += v.y; s.z += v.z; s.w += v.w;
    }
  }
  return s;
}

// pool2: max over WORK members only; non-work x2 rows are implicitly 0, relu>=0 -> 0-init exact.
__device__ __forceinline__ float4 nbr_wmax(const float4* sx4, const int* se, const int* sdeg,
                                           int a, int c4) {
  float4 m = make_float4(0.f, 0.f, 0.f, 0.f);
  if (sdeg[a] < 6) m = max4(m, sx4[a * 32 + c4]);
#pragma unroll
  for (int d = 0; d < 6; ++d) {
    int e = se[a * 6 + d];
    if (e >= 0 && sdeg[e] < 6) m = max4(m, sx4[e * 32 + c4]);
  }
  return m;
}

__global__ __launch_bounds__(256, 4) void qsar_fused(
    const float* __restrict__ atoms, const float* __restrict__ bonds,
    const int* __restrict__ edges,
    const float* __restrict__ W1, const float* __restrict__ b1,
    const float* __restrict__ W2, const float* __restrict__ b2,
    const float* __restrict__ Wo, const float* __restrict__ bo,
    const float* __restrict__ Wm1, const float* __restrict__ bm1,
    const float* __restrict__ Wm2, const float* __restrict__ bm2,
    const float* __restrict__ Wm3, const float* __restrict__ bm3,
    float* __restrict__ out)
{
  const int b    = blockIdx.x;
  const int tid  = threadIdx.x;
  const int wid  = tid >> 6;
  const int hid  = tid >> 5;   // half-wave (group) id 0..7
  const int hl   = tid & 31;   // lane in half-wave

  __shared__ float s_x[64 * 128];     // x1 -> x1p -> ysum -> x2 -> x2p -> logits -> probs
  __shared__ float s_sa[16 * 38];     // chunked summed-atom feats; later aliased fp/h1/h2
  __shared__ float s_bsum[64 * 8];    // bonds.sum(2), pad 8
  __shared__ int   s_edges[64 * 6];
  __shared__ int   s_deg[64];
  __shared__ int   s_work[64];        // deg<6 atoms
  __shared__ int   s_perm[64];        // nonzero-x2p atoms [0,na), zero atoms [na,64)
  __shared__ float s_rsum[64];
  __shared__ int   s_nwork, s_na, s_nz;

  float4* sx4  = reinterpret_cast<float4*>(s_x);
  float*  s_fp = s_sa;                // 256 floats (s_sa dead after conv1)
  float*  s_h1 = s_sa + 256;          // 64
  float*  s_h2 = s_sa + 320;          // 32

  // ---------------- P0: stage edges, bsum; zero s_x; reset counters -------------------
  {
    const int* ge = edges + (size_t)b * (64 * 6);
    for (int i = tid; i < 64 * 6; i += 256) s_edges[i] = ge[i];
    const float* gb = bonds + (size_t)b * (64 * 36);
    for (int i = tid; i < 64 * 6; i += 256) {
      int a = i / 6, f = i - a * 6;
      float s = 0.f;
#pragma unroll
      for (int d = 0; d < 6; ++d) s += gb[a * 36 + d * 6 + f];
      s_bsum[a * 8 + f] = s;
    }
#pragma unroll
    for (int j = 0; j < 8; ++j) sx4[tid + j * 256] = make_float4(0.f, 0.f, 0.f, 0.f);
    if (tid == 0) { s_nwork = 0; s_na = 0; s_nz = 0; }
  }
  __syncthreads();

  // ---------------- P0b: degree + worklist --------------------------------------------
  if (tid < 64) {
    int dcnt = 0;
#pragma unroll
    for (int d = 0; d < 6; ++d) dcnt += (s_edges[tid * 6 + d] >= 0) ? 1 : 0;
    s_deg[tid] = dcnt;
    if (dcnt < 6) { int p = atomicAdd(&s_nwork, 1); s_work[p] = tid; }
  }
  __syncthreads();

  // ---------------- P0c: perm (nonzero-x2p first; read only in P5) --------------------
  if (tid < 64) {
    int nzf = (s_deg[tid] < 6) ? 1 : 0;
#pragma unroll
    for (int d = 0; d < 6; ++d) {
      int e = s_edges[tid * 6 + d];
      if (e >= 0 && s_deg[e] < 6) nzf = 1;
    }
    if (nzf) { int p = atomicAdd(&s_na, 1); s_perm[p] = tid; }
    else     { int p = atomicAdd(&s_nz, 1); s_perm[63 - p] = tid; }
  }

  // ---------------- P1: conv1, half-wave GEMVs, chunks of <=16 work atoms -------------
  {
    const int nw = s_nwork;
    const float* ga = atoms + (size_t)b * (64 * 37);
    const int c0 = hl * 4;
    for (int cb = 0; cb < nw; cb += 16) {
      const int cnt = (nw - cb < 16) ? (nw - cb) : 16;
      // gather summed feats (self + valid members) from global into s_sa
      for (int i = tid; i < cnt * 37; i += 256) {
        int wi = i / 37, k = i - wi * 37;
        int a = s_work[cb + wi];
        float f = ga[a * 37 + k];
#pragma unroll
        for (int d = 0; d < 6; ++d) {
          int e = s_edges[a * 6 + d];
          if (e >= 0) f += ga[e * 37 + k];
        }
        s_sa[wi * 38 + k] = f;
      }
      __syncthreads();
      // half-wave GEMV: 4 cols/lane, float4 weight rows; writes own s_x row (pre-zeroed)
      for (int w = hid; w < cnt; w += 8) {
        const int a = s_work[cb + w];
        const int d = s_deg[a];
        const float* wp = W1 + d * (43 * 128);
        float4 acc = *reinterpret_cast<const float4*>(&b1[d * 128 + c0]);
#pragma unroll 4
        for (int k = 0; k < 37; ++k) {
          const float f = s_sa[w * 38 + k];
          const float4 w4 = *reinterpret_cast<const float4*>(&wp[k * 128 + c0]);
          acc.x = fmaf(f, w4.x, acc.x); acc.y = fmaf(f, w4.y, acc.y);
          acc.z = fmaf(f, w4.z, acc.z); acc.w = fmaf(f, w4.w, acc.w);
        }
#pragma unroll
        for (int kk = 0; kk < 6; ++kk) {
          const float f = s_bsum[a * 8 + kk];
          const float4 w4 = *reinterpret_cast<const float4*>(&wp[(37 + kk) * 128 + c0]);
          acc.x = fmaf(f, w4.x, acc.x); acc.y = fmaf(f, w4.y, acc.y);
          acc.z = fmaf(f, w4.z, acc.z); acc.w = fmaf(f, w4.w, acc.w);
        }
        *reinterpret_cast<float4*>(&s_x[a * 128 + c0]) =
            make_float4(fmaxf(acc.x, 0.f), fmaxf(acc.y, 0.f),
                        fmaxf(acc.z, 0.f), fmaxf(acc.w, 0.f));
      }
      __syncthreads();
    }
  }
  __syncthreads();

  // ---------------- P2: pool1 in place (all rows), float4 -----------------------------
  {
    float4 v0 = nbr_max(sx4, s_edges, (tid + 0 * 256) >> 5, tid & 31);
    float4 v1 = nbr_max(sx4, s_edges, (tid + 1 * 256) >> 5, tid & 31);
    float4 v2 = nbr_max(sx4, s_edges, (tid + 2 * 256) >> 5, tid & 31);
    float4 v3 = nbr_max(sx4, s_edges, (tid + 3 * 256) >> 5, tid & 31);
    float4 v4 = nbr_max(sx4, s_edges, (tid + 4 * 256) >> 5, tid & 31);
    float4 v5 = nbr_max(sx4, s_edges, (tid + 5 * 256) >> 5, tid & 31);
    float4 v6 = nbr_max(sx4, s_edges, (tid + 6 * 256) >> 5, tid & 31);
    float4 v7 = nbr_max(sx4, s_edges, (tid + 7 * 256) >> 5, tid & 31);
    __syncthreads();
    sx4[tid + 0 * 256] = v0; sx4[tid + 1 * 256] = v1;
    sx4[tid + 2 * 256] = v2; sx4[tid + 3 * 256] = v3;
    sx4[tid + 4 * 256] = v4; sx4[tid + 5 * 256] = v5;
    sx4[tid + 6 * 256] = v6; sx4[tid + 7 * 256] = v7;
  }
  __syncthreads();

  // ---------------- P2b: ysum for work rows in place ----------------------------------
  {
    const float4 z = make_float4(0.f, 0.f, 0.f, 0.f);
    float4 v0 = z, v1 = z, v2 = z, v3 = z, v4 = z, v5 = z, v6 = z, v7 = z;
    if (s_deg[(tid + 0 * 256) >> 5] < 6) v0 = nbr_sum(sx4, s_edges, (tid + 0 * 256) >> 5, tid & 31);
    if (s_deg[(tid + 1 * 256) >> 5] < 6) v1 = nbr_sum(sx4, s_edges, (tid + 1 * 256) >> 5, tid & 31);
    if (s_deg[(tid + 2 * 256) >> 5] < 6) v2 = nbr_sum(sx4, s_edges, (tid + 2 * 256) >> 5, tid & 31);
    if (s_deg[(tid + 3 * 256) >> 5] < 6) v3 = nbr_sum(sx4, s_edges, (tid + 3 * 256) >> 5, tid & 31);
    if (s_deg[(tid + 4 * 256) >> 5] < 6) v4 = nbr_sum(sx4, s_edges, (tid + 4 * 256) >> 5, tid & 31);
    if (s_deg[(tid + 5 * 256) >> 5] < 6) v5 = nbr_sum(sx4, s_edges, (tid + 5 * 256) >> 5, tid & 31);
    if (s_deg[(tid + 6 * 256) >> 5] < 6) v6 = nbr_sum(sx4, s_edges, (tid + 6 * 256) >> 5, tid & 31);
    if (s_deg[(tid + 7 * 256) >> 5] < 6) v7 = nbr_sum(sx4, s_edges, (tid + 7 * 256) >> 5, tid & 31);
    __syncthreads();
    if (s_deg[(tid + 0 * 256) >> 5] < 6) sx4[tid + 0 * 256] = v0;
    if (s_deg[(tid + 1 * 256) >> 5] < 6) sx4[tid + 1 * 256] = v1;
    if (s_deg[(tid + 2 * 256) >> 5] < 6) sx4[tid + 2 * 256] = v2;
    if (s_deg[(tid + 3 * 256) >> 5] < 6) sx4[tid + 3 * 256] = v3;
    if (s_deg[(tid + 4 * 256) >> 5] < 6) sx4[tid + 4 * 256] = v4;
    if (s_deg[(tid + 5 * 256) >> 5] < 6) sx4[tid + 5 * 256] = v5;
    if (s_deg[(tid + 6 * 256) >> 5] < 6) sx4[tid + 6 * 256] = v6;
    if (s_deg[(tid + 7 * 256) >> 5] < 6) sx4[tid + 7 * 256] = v7;
  }
  __syncthreads();

  // ---------------- P3: conv2, half-wave GEMVs, own-row read/write --------------------
  // All 128 reads of row a precede the (same-wave, in-order) write. Rows disjoint.
  {
    const int nw = s_nwork;
    const int c0 = hl * 4;
    for (int w = hid; w < nw; w += 8) {
      const int a = s_work[w];
      const int d = s_deg[a];
      const float* wp = W2 + d * (134 * 128);
      float4 acc = *reinterpret_cast<const float4*>(&b2[d * 128 + c0]);
#pragma unroll 4
      for (int k = 0; k < 128; ++k) {
        const float f = s_x[a * 128 + k];
        const float4 w4 = *reinterpret_cast<const float4*>(&wp[k * 128 + c0]);
        acc.x = fmaf(f, w4.x, acc.x); acc.y = fmaf(f, w4.y, acc.y);
        acc.z = fmaf(f, w4.z, acc.z); acc.w = fmaf(f, w4.w, acc.w);
      }
#pragma unroll
      for (int kk = 0; kk < 6; ++kk) {
        const float f = s_bsum[a * 8 + kk];
        const float4 w4 = *reinterpret_cast<const float4*>(&wp[(128 + kk) * 128 + c0]);
        acc.x = fmaf(f, w4.x, acc.x); acc.y = fmaf(f, w4.y, acc.y);
        acc.z = fmaf(f, w4.z, acc.z); acc.w = fmaf(f, w4.w, acc.w);
      }
      *reinterpret_cast<float4*>(&s_x[a * 128 + c0]) =
          make_float4(fmaxf(acc.x, 0.f), fmaxf(acc.y, 0.f),
                      fmaxf(acc.z, 0.f), fmaxf(acc.w, 0.f));
    }
  }
  __syncthreads();

  // ---------------- P4: pool2 in place, work members only, 0-init ---------------------
  {
    float4 v0 = nbr_wmax(sx4, s_edges, s_deg, (tid + 0 * 256) >> 5, tid & 31);
    float4 v1 = nbr_wmax(sx4, s_edges, s_deg, (tid + 1 * 256) >> 5, tid & 31);
    float4 v2 = nbr_wmax(sx4, s_edges, s_deg, (tid + 2 * 256) >> 5, tid & 31);
    float4 v3 = nbr_wmax(sx4, s_edges, s_deg, (tid + 3 * 256) >> 5, tid & 31);
    float4 v4 = nbr_wmax(sx4, s_edges, s_deg, (tid + 4 * 256) >> 5, tid & 31);
    float4 v5 = nbr_wmax(sx4, s_edges, s_deg, (tid + 5 * 256) >> 5, tid & 31);
    float4 v6 = nbr_wmax(sx4, s_edges, s_deg, (tid + 6 * 256) >> 5, tid & 31);
    float4 v7 = nbr_wmax(sx4, s_edges, s_deg, (tid + 7 * 256) >> 5, tid & 31);
    __syncthreads();
    sx4[tid + 0 * 256] = v0; sx4[tid + 1 * 256] = v1;
    sx4[tid + 2 * 256] = v2; sx4[tid + 3 * 256] = v3;
    sx4[tid + 4 * 256] = v4; sx4[tid + 5 * 256] = v5;
    sx4[tid + 6 * 256] = v6; sx4[tid + 7 * 256] = v7;
  }
  __syncthreads();

  // ---------------- P5: logits GEMM, balanced: 4 perm atoms per group per round -------
  // nr = ceil(na/32) rounds (block-uniform). Round j: group ag owns slots 32j+4ag..+3.
  // Reads (x2p rows) and writes (logits rows) are separated by one sync per round; rows
  // written in round j are never read in rounds > j (disjoint slot ranges). Slots >= na
  // read zero rows (adds 0) and skip the write. Zero rows get the cheap bsum-only path.
  {
    const int cg = tid & 31, ag = hid;
    const int c0 = cg * 4;
    const int na = s_na;
    const int nr = (na + 31) >> 5;
    for (int j = 0; j < nr; ++j) {
      const int sl = j * 32 + ag * 4;
      const int at0 = s_perm[sl + 0], at1 = s_perm[sl + 1];
      const int at2 = s_perm[sl + 2], at3 = s_perm[sl + 3];
      float a00 = 0.f, a01 = 0.f, a02 = 0.f, a03 = 0.f;
      float a10 = 0.f, a11 = 0.f, a12 = 0.f, a13 = 0.f;
      float a20 = 0.f, a21 = 0.f, a22 = 0.f, a23 = 0.f;
      float a30 = 0.f, a31 = 0.f, a32 = 0.f, a33 = 0.f;
      if (j * 32 + wid * 8 < na) {   // wave-uniform skip
#pragma unroll 4
        for (int k = 0; k < 128; ++k) {
          const float4 w4 = *reinterpret_cast<const float4*>(Wo + k * 128 + c0);
          const float f0 = s_x[at0 * 128 + k], f1 = s_x[at1 * 128 + k];
          const float f2 = s_x[at2 * 128 + k], f3 = s_x[at3 * 128 + k];
          a00 = fmaf(f0, w4.x, a00); a01 = fmaf(f0, w4.y, a01);
          a02 = fmaf(f0, w4.z, a02); a03 = fmaf(f0, w4.w, a03);
          a10 = fmaf(f1, w4.x, a10); a11 = fmaf(f1, w4.y, a11);
          a12 = fmaf(f1, w4.z, a12); a13 = fmaf(f1, w4.w, a13);
          a20 = fmaf(f2, w4.x, a20); a21 = fmaf(f2, w4.y, a21);
          a22 = fmaf(f2, w4.z, a22); a23 = fmaf(f2, w4.w, a23);
          a30 = fmaf(f3, w4.x, a30); a31 = fmaf(f3, w4.y, a31);
          a32 = fmaf(f3, w4.z, a32); a33 = fmaf(f3, w4.w, a33);
        }
#pragma unroll
        for (int kk = 0; kk < 6; ++kk) {
          const float4 w4 = *reinterpret_cast<const float4*>(Wo + (128 + kk) * 128 + c0);
          const float f0 = s_bsum[at0 * 8 + kk], f1 = s_bsum[at1 * 8 + kk];
          const float f2 = s_bsum[at2 * 8 + kk], f3 = s_bsum[at3 * 8 + kk];
          a00 = fmaf(f0, w4.x, a00); a01 = fmaf(f0, w4.y, a01);
          a02 = fmaf(f0, w4.z, a02); a03 = fmaf(f0, w4.w, a03);
          a10 = fmaf(f1, w4.x, a10); a11 = fmaf(f1, w4.y, a11);
          a12 = fmaf(f1, w4.z, a12); a13 = fmaf(f1, w4.w, a13);
          a20 = fmaf(f2, w4.x, a20); a21 = fmaf(f2, w4.y, a21);
          a22 = fmaf(f2, w4.z, a22); a23 = fmaf(f2, w4.w, a23);
          a30 = fmaf(f3, w4.x, a30); a31 = fmaf(f3, w4.y, a31);
          a32 = fmaf(f3, w4.z, a32); a33 = fmaf(f3, w4.w, a33);
        }
      }
      __syncthreads();   // separate this round's reads from its writes (all threads)
      const float4 bo4 = *reinterpret_cast<const float4*>(bo + c0);
      if (sl + 0 < na)
        *reinterpret_cast<float4*>(&s_x[at0 * 128 + c0]) =
            make_float4(a00 + bo4.x, a01 + bo4.y, a02 + bo4.z, a03 + bo4.w);
      if (sl + 1 < na)
        *reinterpret_cast<float4*>(&s_x[at1 * 128 + c0]) =
            make_float4(a10 + bo4.x, a11 + bo4.y, a12 + bo4.z, a13 + bo4.w);
      if (sl + 2 < na)
        *reinterpret_cast<float4*>(&s_x[at2 * 128 + c0]) =
            make_float4(a20 + bo4.x, a21 + bo4.y, a22 + bo4.z, a23 + bo4.w);
      if (sl + 3 < na)
        *reinterpret_cast<float4*>(&s_x[at3 * 128 + c0]) =
            make_float4(a30 + bo4.x, a31 + bo4.y, a32 + bo4.z, a33 + bo4.w);
    }
    // zero-x2p atoms: logits = bo + bsum . Wo[128:134] (disjoint rows; after final sync)
    const int nz = 64 - na;
    for (int e = tid; e < nz * 128; e += 256) {
      int zi = e >> 7, c = e & 127;
      int a = s_perm[na + zi];
      float acc = bo[c];
#pragma unroll
      for (int kk = 0; kk < 6; ++kk)
        acc = fmaf(s_bsum[a * 8 + kk], Wo[(128 + kk) * 128 + c], acc);
      s_x[a * 128 + c] = acc;
    }
  }
  __syncthreads();

  // ---------------- P6: per-atom softmax over 128, 4 lanes/atom, in registers ---------
  {
    const int a = tid >> 2, q = tid & 3;
    float* base = &s_x[a * 128 + q * 32];
    // swizzled b128 loads: slot j -> channel block ((j+tid)&7); order-invariant reduce
    const float4 v0 = *reinterpret_cast<const float4*>(base + ((0 + tid) & 7) * 4);
    const float4 v1 = *reinterpret_cast<const float4*>(base + ((1 + tid) & 7) * 4);
    const float4 v2 = *reinterpret_cast<const float4*>(base + ((2 + tid) & 7) * 4);
    const float4 v3 = *reinterpret_cast<const float4*>(base + ((3 + tid) & 7) * 4);
    const float4 v4 = *reinterpret_cast<const float4*>(base + ((4 + tid) & 7) * 4);
    const float4 v5 = *reinterpret_cast<const float4*>(base + ((5 + tid) & 7) * 4);
    const float4 v6 = *reinterpret_cast<const float4*>(base + ((6 + tid) & 7) * 4);
    const float4 v7 = *reinterpret_cast<const float4*>(base + ((7 + tid) & 7) * 4);
    float mx = fmaxf(fmaxf(fmaxf(v0.x, v0.y), fmaxf(v0.z, v0.w)),
                     fmaxf(fmaxf(v1.x, v1.y), fmaxf(v1.z, v1.w)));
    mx = fmaxf(mx, fmaxf(fmaxf(fmaxf(v2.x, v2.y), fmaxf(v2.z, v2.w)),
                         fmaxf(fmaxf(v3.x, v3.y), fmaxf(v3.z, v3.w))));
    mx = fmaxf(mx, fmaxf(fmaxf(fmaxf(v4.x, v4.y), fmaxf(v4.z, v4.w)),
                         fmaxf(fmaxf(v5.x, v5.y), fmaxf(v5.z, v5.w))));
    mx = fmaxf(mx, fmaxf(fmaxf(fmaxf(v6.x, v6.y), fmaxf(v6.z, v6.w)),
                         fmaxf(fmaxf(v7.x, v7.y), fmaxf(v7.z, v7.w))));
    mx = fmaxf(mx, __shfl_xor(mx, 1));
    mx = fmaxf(mx, __shfl_xor(mx, 2));
    float sm = 0.f;
    float4 e0, e1, e2, e3, e4, e5, e6, e7;
    e0.x = __expf(v0.x - mx); e0.y = __expf(v0.y - mx); e0.z = __expf(v0.z - mx); e0.w = __expf(v0.w - mx);
    e1.x = __expf(v1.x - mx); e1.y = __expf(v1.y - mx); e1.z = __expf(v1.z - mx); e1.w = __expf(v1.w - mx);
    e2.x = __expf(v2.x - mx); e2.y = __expf(v2.y - mx); e2.z = __expf(v2.z - mx); e2.w = __expf(v2.w - mx);
    e3.x = __expf(v3.x - mx); e3.y = __expf(v3.y - mx); e3.z = __expf(v3.z - mx); e3.w = __expf(v3.w - mx);
    e4.x = __expf(v4.x - mx); e4.y = __expf(v4.y - mx); e4.z = __expf(v4.z - mx); e4.w = __expf(v4.w - mx);
    e5.x = __expf(v5.x - mx); e5.y = __expf(v5.y - mx); e5.z = __expf(v5.z - mx); e5.w = __expf(v5.w - mx);
    e6.x = __expf(v6.x - mx); e6.y = __expf(v6.y - mx); e6.z = __expf(v6.z - mx); e6.w = __expf(v6.w - mx);
    e7.x = __expf(v7.x - mx); e7.y = __expf(v7.y - mx); e7.z = __expf(v7.z - mx); e7.w = __expf(v7.w - mx);
    sm += e0.x + e0.y + e0.z + e0.w; sm += e1.x + e1.y + e1.z + e1.w;
    sm += e2.x + e2.y + e2.z + e2.w; sm += e3.x + e3.y + e3.z + e3.w;
    sm += e4.x + e4.y + e4.z + e4.w; sm += e5.x + e5.y + e5.z + e5.w;
    sm += e6.x + e6.y + e6.z + e6.w; sm += e7.x + e7.y + e7.z + e7.w;
    *reinterpret_cast<float4*>(base + ((0 + tid) & 7) * 4) = e0;
    *reinterpret_cast<float4*>(base + ((1 + tid) & 7) * 4) = e1;
    *reinterpret_cast<float4*>(base + ((2 + tid) & 7) * 4) = e2;
    *reinterpret_cast<float4*>(base + ((3 + tid) & 7) * 4) = e3;
    *reinterpret_cast<float4*>(base + ((4 + tid) & 7) * 4) = e4;
    *reinterpret_cast<float4*>(base + ((5 + tid) & 7) * 4) = e5;
    *reinterpret_cast<float4*>(base + ((6 + tid) & 7) * 4) = e6;
    *reinterpret_cast<float4*>(base + ((7 + tid) & 7) * 4) = e7;
    sm += __shfl_xor(sm, 1);
    sm += __shfl_xor(sm, 2);
    if (q == 0) s_rsum[a] = (s_deg[a] != 0) ? (1.f / sm) : 0.f;
  }
  __syncthreads();

  // ---------------- P7: fingerprint (s_fp aliases dead s_sa) --------------------------
  {
    const int c = tid & 127, half = tid >> 7;
    float s = 0.f;
    for (int a2 = half * 32; a2 < half * 32 + 32; ++a2)
      s = fmaf(s_x[a2 * 128 + c], s_rsum[a2], s);
    s_fp[half * 128 + c] = s;
  }
  __syncthreads();
  if (tid < 128) s_fp[tid] += s_fp[128 + tid];
  __syncthreads();

  // ---------------- P8: MLP head ------------------------------------------------------
  if (tid < 64) {
    float acc = bm1[tid];
    for (int k = 0; k < 128; ++k) acc = fmaf(s_fp[k], Wm1[k * 64 + tid], acc);
    s_h1[tid] = fmaxf(acc, 0.f);
  }
  __syncthreads();
  if (tid < 32) {
    float acc = bm2[tid];
    for (int k = 0; k < 64; ++k) acc = fmaf(s_h1[k], Wm2[k * 32 + tid], acc);
    s_h2[tid] = fmaxf(acc, 0.f);
  }
  __syncthreads();
  if (tid < 64) {
    float p = (tid < 32) ? s_h2[tid] * Wm3[tid] : 0.f;
#pragma unroll
    for (int off = 32; off > 0; off >>= 1) p += __shfl_xor(p, off);
    if (tid == 0) out[b] = p + bm3[0];
  }
}

extern "C" void kernel_launch(void* const* d_in, const int* in_sizes, int n_in,
                              void* d_out, int out_size, void* d_ws, size_t ws_size,
                              hipStream_t stream) {
  const float* atoms = (const float*)d_in[0];
  const float* bonds = (const float*)d_in[1];
  const int*   edges = (const int*)d_in[2];
  const float* W1  = (const float*)d_in[3];
  const float* b1  = (const float*)d_in[4];
  const float* W2  = (const float*)d_in[5];
  const float* b2  = (const float*)d_in[6];
  const float* Wo  = (const float*)d_in[7];
  const float* bo  = (const float*)d_in[8];
  const float* Wm1 = (const float*)d_in[9];
  const float* bm1 = (const float*)d_in[10];
  const float* Wm2 = (const float*)d_in[11];
  const float* bm2 = (const float*)d_in[12];
  const float* Wm3 = (const float*)d_in[13];
  const float* bm3 = (const float*)d_in[14];
  float* out = (float*)d_out;

  const int B = out_size;  // 4096 molecules
  qsar_fused<<<dim3(B), dim3(256), 0, stream>>>(
      atoms, bonds, edges, W1, b1, W2, b2, Wo, bo,
      Wm1, bm1, Wm2, bm2, Wm3, bm3, out);
}